// Round 1
// baseline (1267.475 us; speedup 1.0000x reference)
//
#include <hip/hip_runtime.h>
#include <math.h>

#define PLANE 9216        // 96*96
#define VOL   884736      // 96*96*96
#define NC    4
#define K     7
#define HSR   3
#define SEG   32
#define NSEG  3           // 96/SEG

// ---------------- tables: 1D taps + boundary sums ----------------
__global__ void tables_kernel(const float* __restrict__ sigma2,
                              const float* __restrict__ sigma3,
                              float* __restrict__ taps2, float* __restrict__ taps3,
                              float* __restrict__ B2, float* __restrict__ B3)
{
    int t = threadIdx.x;
    if (t < 2 * NC) {
        int c = t % NC;
        const float* sig = (t < NC) ? sigma2 : sigma3;
        float* taps = (t < NC) ? taps2 : taps3;
        float sv = sig[c];
        float s2 = sv * sv;
        float w[K];
        float sum = 0.f;
        for (int j = 0; j < K; j++) {
            float d = (float)(j - HSR);
            w[j] = expf(-d * d / (2.f * s2));
            sum += w[j];
        }
        float inv = 1.f / sum;   // sum3d = sum^3; per-axis norm by sum reproduces it
        for (int j = 0; j < K; j++) taps[c * K + j] = w[j] * inv;
    }
    __syncthreads();
    for (int i = t; i < NC * 96; i += blockDim.x) {
        int c = i / 96, p = i % 96;
        float s2v = 0.f, s3v = 0.f;
        for (int j = 0; j < K; j++) {
            int q = p + j - HSR;
            if (q >= 0 && q < 96) { s2v += taps2[c * K + j]; s3v += taps3[c * K + j]; }
        }
        B2[i] = s2v;
        B3[i] = s3v;
    }
}

// ---------------- initial softmax over C ----------------
__global__ __launch_bounds__(256) void softmax0_kernel(const float* __restrict__ o,
                                                       const float* __restrict__ eta,
                                                       float* __restrict__ u)
{
    int i = blockIdx.x * 256 + threadIdx.x;
    float inv_eta = 1.f / eta[0];
    float a0 = o[i] * inv_eta;
    float a1 = o[i + VOL] * inv_eta;
    float a2 = o[i + 2 * VOL] * inv_eta;
    float a3 = o[i + 3 * VOL] * inv_eta;
    float m = fmaxf(fmaxf(a0, a1), fmaxf(a2, a3));
    float e0 = __expf(a0 - m), e1 = __expf(a1 - m), e2 = __expf(a2 - m), e3 = __expf(a3 - m);
    float inv = 1.f / (e0 + e1 + e2 + e3);
    u[i] = e0 * inv;
    u[i + VOL] = e1 * inv;
    u[i + 2 * VOL] = e2 * inv;
    u[i + 3 * VOL] = e3 * inv;
}

// ---------------- P1: z-conv of {u*I, u (ker_lif), u (ker)} ----------------
__global__ __launch_bounds__(256) void pass1_z(const float* __restrict__ u,
                                               const float* __restrict__ I,
                                               const float* __restrict__ taps2,
                                               const float* __restrict__ taps3,
                                               float* __restrict__ a0, float* __restrict__ a1,
                                               float* __restrict__ a2)
{
    int id = blockIdx.x * 256 + threadIdx.x;
    int p  = id % PLANE;
    int cs = id / PLANE;
    int s  = cs % NSEG;
    int c  = cs / NSEG;
    int z0 = s * SEG;
    const float* ub = u + c * VOL + p;
    const float* Ib = I + p;
    float t3[K], t2[K];
#pragma unroll
    for (int j = 0; j < K; j++) { t3[j] = taps3[c * K + j]; t2[j] = taps2[c * K + j]; }
    float wu[K], wui[K];
#pragma unroll
    for (int j = 0; j < K - 1; j++) {
        int z = z0 + j - HSR;
        float uv = 0.f, iv = 0.f;
        if (z >= 0 && z < 96) { uv = ub[z * PLANE]; iv = Ib[z * PLANE]; }
        wu[j] = uv; wui[j] = uv * iv;
    }
    float* o0 = a0 + c * VOL + p;
    float* o1 = a1 + c * VOL + p;
    float* o2 = a2 + c * VOL + p;
    for (int k = 0; k < SEG; k++) {
        int z = z0 + k;
        int zl = z + HSR;
        float uv = 0.f, iv = 0.f;
        if (zl < 96) { uv = ub[zl * PLANE]; iv = Ib[zl * PLANE]; }
        wu[K - 1] = uv; wui[K - 1] = uv * iv;
        float s0 = 0.f, s1 = 0.f, s2 = 0.f;
#pragma unroll
        for (int j = 0; j < K; j++) { s0 += t3[j] * wui[j]; s1 += t3[j] * wu[j]; s2 += t2[j] * wu[j]; }
        o0[z * PLANE] = s0;
        o1[z * PLANE] = s1;
        o2[z * PLANE] = s2;
#pragma unroll
        for (int j = 0; j < K - 1; j++) { wu[j] = wu[j + 1]; wui[j] = wui[j + 1]; }
    }
}

// ---------------- P2: y-conv of 3 fields ----------------
__global__ __launch_bounds__(256) void pass2_y(const float* __restrict__ a0,
                                               const float* __restrict__ a1,
                                               const float* __restrict__ a2,
                                               const float* __restrict__ taps2,
                                               const float* __restrict__ taps3,
                                               float* __restrict__ b0, float* __restrict__ b1,
                                               float* __restrict__ b2)
{
    int id = blockIdx.x * 256 + threadIdx.x;
    int x  = id % 96;
    int z  = (id / 96) % 96;
    int cs = id / PLANE;
    int s  = cs % NSEG;
    int c  = cs / NSEG;
    int y0 = s * SEG;
    int base = c * VOL + z * PLANE + x;
    const float* i0 = a0 + base;
    const float* i1 = a1 + base;
    const float* i2 = a2 + base;
    float t3[K], t2[K];
#pragma unroll
    for (int j = 0; j < K; j++) { t3[j] = taps3[c * K + j]; t2[j] = taps2[c * K + j]; }
    float w0[K], w1[K], w2[K];
#pragma unroll
    for (int j = 0; j < K - 1; j++) {
        int y = y0 + j - HSR;
        float v0 = 0.f, v1 = 0.f, v2 = 0.f;
        if (y >= 0 && y < 96) { v0 = i0[y * 96]; v1 = i1[y * 96]; v2 = i2[y * 96]; }
        w0[j] = v0; w1[j] = v1; w2[j] = v2;
    }
    for (int k = 0; k < SEG; k++) {
        int y = y0 + k, yl = y + HSR;
        float v0 = 0.f, v1 = 0.f, v2 = 0.f;
        if (yl < 96) { v0 = i0[yl * 96]; v1 = i1[yl * 96]; v2 = i2[yl * 96]; }
        w0[K - 1] = v0; w1[K - 1] = v1; w2[K - 1] = v2;
        float s0 = 0.f, s1 = 0.f, s2 = 0.f;
#pragma unroll
        for (int j = 0; j < K; j++) { s0 += t3[j] * w0[j]; s1 += t3[j] * w1[j]; s2 += t2[j] * w2[j]; }
        b0[base + y * 96] = s0;
        b1[base + y * 96] = s1;
        b2[base + y * 96] = s2;
#pragma unroll
        for (int j = 0; j < K - 1; j++) { w0[j] = w0[j + 1]; w1[j] = w1[j + 1]; w2[j] = w2[j + 1]; }
    }
}

// ---------------- P3: x-conv + Cn + q ----------------
__global__ __launch_bounds__(256) void pass3_x(const float* __restrict__ b0,
                                               const float* __restrict__ b1,
                                               const float* __restrict__ b2,
                                               const float* __restrict__ taps2,
                                               const float* __restrict__ taps3,
                                               const float* __restrict__ B2,
                                               float* __restrict__ Cn, float* __restrict__ q)
{
    int id = blockIdx.x * 256 + threadIdx.x;
    int c = id / VOL;
    int r = id % VOL;
    int x = r % 96;
    int y = (r / 96) % 96;
    int z = r / PLANE;
    int rowbase = id - x;
    float t3[K], t2[K];
#pragma unroll
    for (int j = 0; j < K; j++) { t3[j] = taps3[c * K + j]; t2[j] = taps2[c * K + j]; }
    float s0 = 0.f, s1 = 0.f, s2 = 0.f;
#pragma unroll
    for (int j = 0; j < K; j++) {
        int xx = x + j - HSR;
        if (xx >= 0 && xx < 96) {
            s0 += t3[j] * b0[rowbase + xx];
            s1 += t3[j] * b1[rowbase + xx];
            s2 += t2[j] * b2[rowbase + xx];
        }
    }
    float Cnv = (s0 + 1e-6f) / (s1 + 1e-6f);
    float qv = B2[c * 96 + z] * B2[c * 96 + y] * B2[c * 96 + x] - 2.f * s2;
    Cn[id] = Cnv;
    q[id]  = qv;
}

// ---------------- P4: z-conv of {Cn, Cn^2} ----------------
__global__ __launch_bounds__(256) void pass4_z(const float* __restrict__ Cn,
                                               const float* __restrict__ taps3,
                                               float* __restrict__ b0, float* __restrict__ b1)
{
    int id = blockIdx.x * 256 + threadIdx.x;
    int p  = id % PLANE;
    int cs = id / PLANE;
    int s  = cs % NSEG;
    int c  = cs / NSEG;
    int z0 = s * SEG;
    const float* ib = Cn + c * VOL + p;
    float t3[K];
#pragma unroll
    for (int j = 0; j < K; j++) t3[j] = taps3[c * K + j];
    float w[K];
#pragma unroll
    for (int j = 0; j < K - 1; j++) {
        int z = z0 + j - HSR;
        float v = 0.f;
        if (z >= 0 && z < 96) v = ib[z * PLANE];
        w[j] = v;
    }
    float* o0 = b0 + c * VOL + p;
    float* o1 = b1 + c * VOL + p;
    for (int k = 0; k < SEG; k++) {
        int z = z0 + k, zl = z + HSR;
        float v = 0.f;
        if (zl < 96) v = ib[zl * PLANE];
        w[K - 1] = v;
        float s0 = 0.f, s1 = 0.f;
#pragma unroll
        for (int j = 0; j < K; j++) { s0 += t3[j] * w[j]; s1 += t3[j] * w[j] * w[j]; }
        o0[z * PLANE] = s0;
        o1[z * PLANE] = s1;
#pragma unroll
        for (int j = 0; j < K - 1; j++) w[j] = w[j + 1];
    }
}

// ---------------- P5: y-conv of 2 fields ----------------
__global__ __launch_bounds__(256) void pass5_y(const float* __restrict__ b0,
                                               const float* __restrict__ b1,
                                               const float* __restrict__ taps3,
                                               float* __restrict__ d0, float* __restrict__ d1)
{
    int id = blockIdx.x * 256 + threadIdx.x;
    int x  = id % 96;
    int z  = (id / 96) % 96;
    int cs = id / PLANE;
    int s  = cs % NSEG;
    int c  = cs / NSEG;
    int y0 = s * SEG;
    int base = c * VOL + z * PLANE + x;
    const float* i0 = b0 + base;
    const float* i1 = b1 + base;
    float t3[K];
#pragma unroll
    for (int j = 0; j < K; j++) t3[j] = taps3[c * K + j];
    float w0[K], w1[K];
#pragma unroll
    for (int j = 0; j < K - 1; j++) {
        int y = y0 + j - HSR;
        float v0 = 0.f, v1 = 0.f;
        if (y >= 0 && y < 96) { v0 = i0[y * 96]; v1 = i1[y * 96]; }
        w0[j] = v0; w1[j] = v1;
    }
    for (int k = 0; k < SEG; k++) {
        int y = y0 + k, yl = y + HSR;
        float v0 = 0.f, v1 = 0.f;
        if (yl < 96) { v0 = i0[yl * 96]; v1 = i1[yl * 96]; }
        w0[K - 1] = v0; w1[K - 1] = v1;
        float s0 = 0.f, s1 = 0.f;
#pragma unroll
        for (int j = 0; j < K; j++) { s0 += t3[j] * w0[j]; s1 += t3[j] * w1[j]; }
        d0[base + y * 96] = s0;
        d1[base + y * 96] = s1;
#pragma unroll
        for (int j = 0; j < K - 1; j++) { w0[j] = w0[j + 1]; w1[j] = w1[j + 1]; }
    }
}

// ---------------- P6: x-conv + Lif + arg + channel softmax ----------------
__global__ __launch_bounds__(256) void pass6_final(const float* __restrict__ D0,
                                                   const float* __restrict__ D1,
                                                   const float* __restrict__ q,
                                                   const float* __restrict__ o,
                                                   const float* __restrict__ I,
                                                   const float* __restrict__ taps3,
                                                   const float* __restrict__ B3,
                                                   const float* __restrict__ eta,
                                                   const float* __restrict__ lam,
                                                   const float* __restrict__ mu,
                                                   float* __restrict__ u)
{
    int v = blockIdx.x * 256 + threadIdx.x;
    int x = v % 96;
    int y = (v / 96) % 96;
    int z = v / PLANE;
    float Iv = I[v];
    float I2v = Iv * Iv;
    float inv_eta = 1.f / eta[0];
    float lamv = lam[0], muv = mu[0];
    int rowbase = v - x;
    float arg[NC];
#pragma unroll
    for (int c = 0; c < NC; c++) {
        const float* d0p = D0 + c * VOL + rowbase;
        const float* d1p = D1 + c * VOL + rowbase;
        float d0 = 0.f, d1 = 0.f;
#pragma unroll
        for (int j = 0; j < K; j++) {
            int xx = x + j - HSR;
            if (xx >= 0 && xx < 96) {
                float t = taps3[c * K + j];
                d0 += t * d0p[xx];
                d1 += t * d1p[xx];
            }
        }
        float cones = B3[c * 96 + z] * B3[c * 96 + y] * B3[c * 96 + x];
        float Lif = d1 - 2.f * Iv * d0 + I2v * cones;
        arg[c] = (o[c * VOL + v] - muv * Lif - lamv * q[c * VOL + v]) * inv_eta;
    }
    float m = fmaxf(fmaxf(arg[0], arg[1]), fmaxf(arg[2], arg[3]));
    float e0 = __expf(arg[0] - m), e1 = __expf(arg[1] - m);
    float e2 = __expf(arg[2] - m), e3 = __expf(arg[3] - m);
    float inv = 1.f / (e0 + e1 + e2 + e3);
    u[v] = e0 * inv;
    u[v + VOL] = e1 * inv;
    u[v + 2 * VOL] = e2 * inv;
    u[v + 3 * VOL] = e3 * inv;
}

extern "C" void kernel_launch(void* const* d_in, const int* in_sizes, int n_in,
                              void* d_out, int out_size, void* d_ws, size_t ws_size,
                              hipStream_t stream)
{
    const float* o      = (const float*)d_in[0];
    const float* I      = (const float*)d_in[1];
    const float* sigma2 = (const float*)d_in[2];
    const float* sigma3 = (const float*)d_in[3];
    const float* eta    = (const float*)d_in[4];
    const float* lam    = (const float*)d_in[5];
    const float* mu     = (const float*)d_in[6];
    float* u = (float*)d_out;

    float* wsf = (float*)d_ws;
    float* taps2 = wsf;              // 28 floats
    float* taps3 = wsf + 32;         // 28 floats
    float* B2    = wsf + 64;         // 384 floats
    float* B3    = wsf + 64 + NC * 96;
    float* buf   = wsf + 1024;
    const size_t VCs = (size_t)NC * VOL;
    float* a0 = buf;
    float* a1 = buf + VCs;
    float* a2 = buf + 2 * VCs;
    float* b0 = buf + 3 * VCs;
    float* b1 = buf + 4 * VCs;
    float* b2 = buf + 5 * VCs;

    const int gridZ = (NC * NSEG * PLANE) / 256;  // 432
    const int gridX = (NC * VOL) / 256;           // 13824
    const int gridV = VOL / 256;                  // 3456

    tables_kernel<<<1, 512, 0, stream>>>(sigma2, sigma3, taps2, taps3, B2, B3);
    softmax0_kernel<<<gridV, 256, 0, stream>>>(o, eta, u);
    for (int it = 0; it < 10; it++) {
        pass1_z<<<gridZ, 256, 0, stream>>>(u, I, taps2, taps3, a0, a1, a2);
        pass2_y<<<gridZ, 256, 0, stream>>>(a0, a1, a2, taps2, taps3, b0, b1, b2);
        pass3_x<<<gridX, 256, 0, stream>>>(b0, b1, b2, taps2, taps3, B2, a0, a1);
        pass4_z<<<gridZ, 256, 0, stream>>>(a0, taps3, b0, b1);
        pass5_y<<<gridZ, 256, 0, stream>>>(b0, b1, taps3, a0, a2);
        pass6_final<<<gridV, 256, 0, stream>>>(a0, a2, a1, o, I, taps3, B3, eta, lam, mu, u);
    }
}